// Round 6
// baseline (250.276 us; speedup 1.0000x reference)
//
#include <hip/hip_runtime.h>
#include <hip/hip_bf16.h>

#define T_TOK 2048
#define HDIM  2048
#define FDIM  1024
#define NEXP  8
#define KSEL  2
#define NENT  (T_TOK*KSEL)   // 4096 routing entries
#define WMAX  24             // max 256-row work items: sum ceil(cnt/256) <= 16+8

typedef __attribute__((ext_vector_type(8))) short   short8v;
typedef __attribute__((ext_vector_type(4))) float   floatx4;
typedef __attribute__((ext_vector_type(4))) unsigned short ushort4v;

__device__ __forceinline__ unsigned short f2bf(float f) {
  unsigned int u = __builtin_bit_cast(unsigned int, f);
  u += 0x7FFFu + ((u >> 16) & 1u);
  return (unsigned short)(u >> 16);
}

__device__ __forceinline__ void gll16(const void* g, void* l) {
  __builtin_amdgcn_global_load_lds(
      (const __attribute__((address_space(1))) unsigned int*)g,
      (__attribute__((address_space(3))) unsigned int*)l, 16, 0, 0);
}

// ---- workspace layout ----
// wsI[0:8) cnt | wsI[8:16) cursor | wsI[16:24) offsets | wsI[24] nWork(256-row items)
// wsI[48:72) work list (e<<8 | block)
// wsI[128:128+4096) entry token | (float*)[4096] entry weight | [4096] inverse map
// byte 65536: hidden_bf (8 MiB) | act (8 MiB) | out_e (32 MiB)
#define ETOK_OFF 128

__global__ void k_count(const int* __restrict__ ids, int* __restrict__ wsI) {
  int g = blockIdx.x * 256 + threadIdx.x;
  if (g < NENT) atomicAdd(&wsI[ids[g] & 7], 1);
}

__global__ void k_scan(int* __restrict__ wsI) {
  int s = 0, nW = 0;
  int* wl = wsI + 48;
  for (int e = 0; e < NEXP; e++) {
    wsI[16 + e] = s;
    int c = wsI[e];
    s += c;
    int nb = (c + 255) >> 8;
    for (int sb = 0; sb < nb; sb++) wl[nW++] = (e << 8) | sb;
  }
  wsI[24] = nW;
}

__global__ void k_scatter(const int* __restrict__ ids, const float* __restrict__ tw,
                          int* __restrict__ wsI) {
  int g = blockIdx.x * 256 + threadIdx.x;
  if (g >= NENT) return;
  int e = ids[g] & 7;
  int pos = atomicAdd(&wsI[8 + e], 1);
  int idx = wsI[16 + e] + pos;
  int*   etok = wsI + ETOK_OFF;
  float* ew   = (float*)(wsI + ETOK_OFF + NENT);
  int*   inv  = wsI + ETOK_OFF + 2 * NENT;
  etok[idx] = g >> 1;
  ew[idx]   = tw[g];
  inv[g]    = idx;
}

__global__ __launch_bounds__(256) void k_cast_h(const float* __restrict__ h,
                                                unsigned short* __restrict__ o) {
  const int N = T_TOK * HDIM / 8;
  for (int c = blockIdx.x * 256 + threadIdx.x; c < N; c += 2048 * 256) {
    const floatx4 v0 = *(const floatx4*)(h + (size_t)c * 8);
    const floatx4 v1 = *(const floatx4*)(h + (size_t)c * 8 + 4);
    short8v r = { (short)f2bf(v0.x), (short)f2bf(v0.y), (short)f2bf(v0.z), (short)f2bf(v0.w),
                  (short)f2bf(v1.x), (short)f2bf(v1.y), (short)f2bf(v1.z), (short)f2bf(v1.w) };
    *(short8v*)(o + (size_t)c * 8) = r;
  }
}

// ---- GEMM1: act = silu(h@Wg^T)*(h@Wu^T); BM=256, 2-phase dbuf; fused dequant ----
// grid (WMAX, 32): y = 32 act cols (B = 32 gate + 32 up rows), BK=64, NT=32.
__global__ __launch_bounds__(256, 2) void k_gemm1n(
    const unsigned short* __restrict__ hb,
    const float* __restrict__ wgu,
    const float* __restrict__ sgu,
    const int* __restrict__ wsI,
    unsigned short* __restrict__ act)
{
  if ((int)blockIdx.x >= wsI[24]) return;
  const int item = wsI[48 + blockIdx.x];
  const int e    = item >> 8;
  const int r0   = (item & 255) << 8;        // 256-row block base
  const int cnt  = wsI[e];
  const int off  = wsI[16 + e];
  const int rem  = cnt - r0;
  const int c0   = blockIdx.y * 32;          // act col base
  const int* etok = wsI + ETOK_OFF;

  __shared__ unsigned short As[2][256][64];  // 64 KB
  __shared__ unsigned short Bs[2][64][64];   // 16 KB

  const int tid  = threadIdx.x;
  const int lane = tid & 63;
  const int w    = tid >> 6;
  const int kg   = lane >> 4;
  const int l15  = lane & 15;
  const int lr   = lane >> 3;
  const int lc   = lane & 7;
  const bool wlive = (w * 64) < rem;         // wave-uniform

  // A: wave w stages + computes rows [w*64, w*64+64)
  unsigned int aoff[8];
#pragma unroll
  for (int i = 0; i < 8; i++) {
    int ra  = w * 64 + i * 8 + lr;
    int swz = (lc ^ (ra & 7)) * 8;
    int ent = r0 + ra; if (ent >= cnt) ent = cnt - 1;
    int tok = etok[off + ent];
    aoff[i] = (unsigned)tok * 2048u + (unsigned)swz;
  }

  // B: 2 chunks per thread (64 rows x 8 chunks)
  const float* bsrc[2];
  const float* bsrow[2];
  int bdst[2];
#pragma unroll
  for (int cc = 0; cc < 2; cc++) {
    int c   = tid + cc * 256;
    int row = c >> 3, ch = c & 7;
    int gr  = (row < 32) ? (c0 + row) : (1024 + c0 + row - 32);
    bsrc[cc]  = &wgu[((size_t)e * 2048 + gr) * 2048 + ch * 8];
    bsrow[cc] = &sgu[e * 256 + (gr >> 7) * 16];
    bdst[cc]  = row * 128 + ((ch ^ (row & 7)) << 4);
  }

  floatx4 acc[4][4] = {};

  // prologue: stage tile 0 into buf 0
  if (wlive) {
#pragma unroll
    for (int i = 0; i < 8; i++)
      gll16(hb + aoff[i], (char*)As[0] + (w * 8 + i) * 1024);
  }
#pragma unroll
  for (int cc = 0; cc < 2; cc++) {
    const floatx4 v0 = *(const floatx4*)(bsrc[cc]);
    const floatx4 v1 = *(const floatx4*)(bsrc[cc] + 4);
    float sc = bsrow[cc][0];
    short8v r = { (short)f2bf(v0.x*sc), (short)f2bf(v0.y*sc), (short)f2bf(v0.z*sc), (short)f2bf(v0.w*sc),
                  (short)f2bf(v1.x*sc), (short)f2bf(v1.y*sc), (short)f2bf(v1.z*sc), (short)f2bf(v1.w*sc) };
    *(short8v*)((char*)Bs[0] + bdst[cc]) = r;
  }
  __syncthreads();

  const int NT = HDIM / 64;
  for (int t = 0; t < NT; t++) {
    const int cur = t & 1, nxt = cur ^ 1;
    const bool more = (t + 1) < NT;
    const int kn = (t + 1) * 64;

    floatx4 v[2][2];
    if (more) {
      if (wlive) {
#pragma unroll
        for (int i = 0; i < 8; i++)
          gll16(hb + aoff[i] + kn, (char*)As[nxt] + (w * 8 + i) * 1024);
      }
#pragma unroll
      for (int cc = 0; cc < 2; cc++) {
        v[cc][0] = *(const floatx4*)(bsrc[cc] + kn);
        v[cc][1] = *(const floatx4*)(bsrc[cc] + kn + 4);
      }
    }

    if (wlive) {
      const char* Ab = (const char*)As[cur];
      const char* Bb = (const char*)Bs[cur];
#pragma unroll
      for (int ks = 0; ks < 2; ks++) {
        short8v a[4], b[4];
#pragma unroll
        for (int m = 0; m < 4; m++) {
          int r = w * 64 + m * 16 + l15;
          a[m] = *(const short8v*)(Ab + r * 128 + (((ks * 4 + kg) ^ (r & 7)) << 4));
        }
#pragma unroll
        for (int n = 0; n < 4; n++) {
          int rb = n * 16 + l15;                 // rows 0..63: 32 gate + 32 up
          b[n] = *(const short8v*)(Bb + rb * 128 + (((ks * 4 + kg) ^ (rb & 7)) << 4));
        }
#pragma unroll
        for (int m = 0; m < 4; m++)
#pragma unroll
          for (int n = 0; n < 4; n++)
            acc[m][n] = __builtin_amdgcn_mfma_f32_16x16x32_bf16(a[m], b[n], acc[m][n], 0, 0, 0);
      }
    }

    if (more) {
#pragma unroll
      for (int cc = 0; cc < 2; cc++) {
        float sc = bsrow[cc][kn >> 7];
        const floatx4 v0 = v[cc][0], v1 = v[cc][1];
        short8v r = { (short)f2bf(v0.x*sc), (short)f2bf(v0.y*sc), (short)f2bf(v0.z*sc), (short)f2bf(v0.w*sc),
                      (short)f2bf(v1.x*sc), (short)f2bf(v1.y*sc), (short)f2bf(v1.z*sc), (short)f2bf(v1.w*sc) };
        *(short8v*)((char*)Bs[nxt] + bdst[cc]) = r;
      }
    }
    __syncthreads();
  }

  if (wlive) {
#pragma unroll
    for (int m = 0; m < 4; m++) {
      int rbase = r0 + w * 64 + m * 16 + kg * 4;
#pragma unroll
      for (int reg = 0; reg < 4; reg++) {
        int rr = rbase + reg;
        if (rr < cnt) {
#pragma unroll
          for (int n = 0; n < 2; n++) {
            float g = acc[m][n][reg];
            float u = acc[m][n + 2][reg];
            float a = g / (1.f + __expf(-g)) * u;
            act[(size_t)(off + rr) * FDIM + c0 + n * 16 + l15] = f2bf(a);
          }
        }
      }
    }
  }
}

// ---- GEMM2: out_e = w_entry * (act @ Wdn^T); BM=256, 2-phase dbuf ----
// grid (WMAX, 32): y = 64 h cols, BK=64, NT=16.
__global__ __launch_bounds__(256, 2) void k_gemm2n(
    const float* __restrict__ wdn,
    const float* __restrict__ sdn,
    const int* __restrict__ wsI,
    const unsigned short* __restrict__ act,
    float* __restrict__ oe)
{
  if ((int)blockIdx.x >= wsI[24]) return;
  const int item = wsI[48 + blockIdx.x];
  const int e    = item >> 8;
  const int r0   = (item & 255) << 8;
  const int cnt  = wsI[e];
  const int off  = wsI[16 + e];
  const int rem  = cnt - r0;
  const int c0   = blockIdx.y * 64;          // h col base
  const float* ew = (const float*)(wsI + ETOK_OFF + NENT);

  __shared__ unsigned short As[2][256][64];  // 64 KB
  __shared__ unsigned short Bs[2][64][64];   // 16 KB

  const int tid  = threadIdx.x;
  const int lane = tid & 63;
  const int w    = tid >> 6;
  const int kg   = lane >> 4;
  const int l15  = lane & 15;
  const int lr   = lane >> 3;
  const int lc   = lane & 7;
  const bool wlive = (w * 64) < rem;

  unsigned int aoff[8];
#pragma unroll
  for (int i = 0; i < 8; i++) {
    int ra  = w * 64 + i * 8 + lr;
    int swz = (lc ^ (ra & 7)) * 8;
    int ent = r0 + ra; if (ent >= cnt) ent = cnt - 1;
    aoff[i] = (unsigned)(off + ent) * 1024u + (unsigned)swz;
  }

  const float* bsrc[2];
  const float* bsrow[2];
  int bdst[2];
#pragma unroll
  for (int cc = 0; cc < 2; cc++) {
    int c   = tid + cc * 256;
    int row = c >> 3, ch = c & 7;
    int gr  = c0 + row;
    bsrc[cc]  = &wdn[((size_t)e * 2048 + gr) * 1024 + ch * 8];
    bsrow[cc] = &sdn[e * 128 + (gr >> 7) * 8];
    bdst[cc]  = row * 128 + ((ch ^ (row & 7)) << 4);
  }

  floatx4 acc[4][4] = {};

  if (wlive) {
#pragma unroll
    for (int i = 0; i < 8; i++)
      gll16(act + aoff[i], (char*)As[0] + (w * 8 + i) * 1024);
  }
#pragma unroll
  for (int cc = 0; cc < 2; cc++) {
    const floatx4 v0 = *(const floatx4*)(bsrc[cc]);
    const floatx4 v1 = *(const floatx4*)(bsrc[cc] + 4);
    float sc = bsrow[cc][0];
    short8v r = { (short)f2bf(v0.x*sc), (short)f2bf(v0.y*sc), (short)f2bf(v0.z*sc), (short)f2bf(v0.w*sc),
                  (short)f2bf(v1.x*sc), (short)f2bf(v1.y*sc), (short)f2bf(v1.z*sc), (short)f2bf(v1.w*sc) };
    *(short8v*)((char*)Bs[0] + bdst[cc]) = r;
  }
  __syncthreads();

  const int NT = FDIM / 64;
  for (int t = 0; t < NT; t++) {
    const int cur = t & 1, nxt = cur ^ 1;
    const bool more = (t + 1) < NT;
    const int kn = (t + 1) * 64;

    floatx4 v[2][2];
    if (more) {
      if (wlive) {
#pragma unroll
        for (int i = 0; i < 8; i++)
          gll16(act + aoff[i] + kn, (char*)As[nxt] + (w * 8 + i) * 1024);
      }
#pragma unroll
      for (int cc = 0; cc < 2; cc++) {
        v[cc][0] = *(const floatx4*)(bsrc[cc] + kn);
        v[cc][1] = *(const floatx4*)(bsrc[cc] + kn + 4);
      }
    }

    if (wlive) {
      const char* Ab = (const char*)As[cur];
      const char* Bb = (const char*)Bs[cur];
#pragma unroll
      for (int ks = 0; ks < 2; ks++) {
        short8v a[4], b[4];
#pragma unroll
        for (int m = 0; m < 4; m++) {
          int r = w * 64 + m * 16 + l15;
          a[m] = *(const short8v*)(Ab + r * 128 + (((ks * 4 + kg) ^ (r & 7)) << 4));
        }
#pragma unroll
        for (int n = 0; n < 4; n++) {
          int rb = n * 16 + l15;
          b[n] = *(const short8v*)(Bb + rb * 128 + (((ks * 4 + kg) ^ (rb & 7)) << 4));
        }
#pragma unroll
        for (int m = 0; m < 4; m++)
#pragma unroll
          for (int n = 0; n < 4; n++)
            acc[m][n] = __builtin_amdgcn_mfma_f32_16x16x32_bf16(a[m], b[n], acc[m][n], 0, 0, 0);
      }
    }

    if (more) {
#pragma unroll
      for (int cc = 0; cc < 2; cc++) {
        float sc = bsrow[cc][kn >> 7];
        const floatx4 v0 = v[cc][0], v1 = v[cc][1];
        short8v r = { (short)f2bf(v0.x*sc), (short)f2bf(v0.y*sc), (short)f2bf(v0.z*sc), (short)f2bf(v0.w*sc),
                      (short)f2bf(v1.x*sc), (short)f2bf(v1.y*sc), (short)f2bf(v1.z*sc), (short)f2bf(v1.w*sc) };
        *(short8v*)((char*)Bs[nxt] + bdst[cc]) = r;
      }
    }
    __syncthreads();
  }

  if (wlive) {
#pragma unroll
    for (int m = 0; m < 4; m++) {
      int rbase = r0 + w * 64 + m * 16 + kg * 4;
#pragma unroll
      for (int reg = 0; reg < 4; reg++) {
        int rr = rbase + reg;
        if (rr < cnt) {
          float wgt = ew[off + rr];
#pragma unroll
          for (int n = 0; n < 4; n++)
            oe[(size_t)(off + rr) * HDIM + c0 + n * 16 + l15] = wgt * acc[m][n][reg];
        }
      }
    }
  }
}

__global__ __launch_bounds__(256) void k_reduce(const int* __restrict__ wsI,
                                                const float* __restrict__ oe,
                                                float* __restrict__ out) {
  int i4 = blockIdx.x * 256 + threadIdx.x;
  if (i4 >= T_TOK * HDIM / 4) return;
  int t  = i4 >> 9;
  int h4 = (i4 & 511) * 4;
  const int* inv = wsI + ETOK_OFF + 2 * NENT;
  int e0 = inv[2 * t], e1 = inv[2 * t + 1];
  floatx4 a = *(const floatx4*)&oe[(size_t)e0 * HDIM + h4];
  floatx4 b = *(const floatx4*)&oe[(size_t)e1 * HDIM + h4];
  floatx4 r = a + b;
  *(floatx4*)&out[(size_t)t * HDIM + h4] = r;
}

// ================= fallback (round-1 passing kernels) =================
__global__ __launch_bounds__(256) void k_gemm1_fb(
    const float* __restrict__ hidden, const float* __restrict__ wgu,
    const float* __restrict__ sgu, const int* __restrict__ wsI,
    unsigned short* __restrict__ act)
{
  const int e = blockIdx.y; const int cnt = wsI[e];
  const int r0 = blockIdx.x * 128; if (r0 >= cnt) return;
  const int off = wsI[16 + e]; const int c0 = blockIdx.z * 64;
  const int* etok = wsI + ETOK_OFF;
  __shared__ unsigned short As[128][40]; __shared__ unsigned short Bs[128][40];
  const int tid = threadIdx.x, lane = tid & 63, wv = tid >> 6;
  const int wr = (wv >> 1) * 64, wc = wv & 1, kg = lane >> 4, l15 = lane & 15;
  floatx4 acc[4][4] = {};
  for (int k0 = 0; k0 < HDIM; k0 += 32) {
#pragma unroll
    for (int c = tid; c < 1024; c += 256) {
      int row = c >> 3, k4 = c & 7;
      int rg = r0 + row; if (rg >= cnt) rg = cnt - 1;
      int tok = etok[off + rg];
      const floatx4 v = *(const floatx4*)&hidden[(size_t)tok * HDIM + k0 + k4 * 4];
      ushort4v o = { f2bf(v.x), f2bf(v.y), f2bf(v.z), f2bf(v.w) };
      *(ushort4v*)&As[row][k4 * 4] = o;
    }
#pragma unroll
    for (int c = tid; c < 1024; c += 256) {
      int row = c >> 3, k4 = c & 7;
      int gr = (row < 64) ? (c0 + row) : (FDIM + c0 + row - 64);
      float s = sgu[e * 256 + (gr >> 7) * 16 + (k0 >> 7)];
      const floatx4 v = *(const floatx4*)&wgu[((size_t)e * 2048 + gr) * HDIM + k0 + k4 * 4];
      ushort4v o = { f2bf(v.x * s), f2bf(v.y * s), f2bf(v.z * s), f2bf(v.w * s) };
      *(ushort4v*)&Bs[row][k4 * 4] = o;
    }
    __syncthreads();
    short8v a[4], b[4];
#pragma unroll
    for (int m = 0; m < 4; m++) a[m] = *(const short8v*)&As[wr + m * 16 + l15][kg * 8];
#pragma unroll
    for (int n = 0; n < 4; n++) {
      int br = (n < 2) ? (wc * 32 + n * 16) : (64 + wc * 32 + (n - 2) * 16);
      b[n] = *(const short8v*)&Bs[br + l15][kg * 8];
    }
#pragma unroll
    for (int m = 0; m < 4; m++)
#pragma unroll
      for (int n = 0; n < 4; n++)
        acc[m][n] = __builtin_amdgcn_mfma_f32_16x16x32_bf16(a[m], b[n], acc[m][n], 0, 0, 0);
    __syncthreads();
  }
#pragma unroll
  for (int m = 0; m < 4; m++) {
    int rbase = r0 + wr + m * 16 + kg * 4;
#pragma unroll
    for (int reg = 0; reg < 4; reg++) {
      int rr = rbase + reg;
      if (rr < cnt) {
#pragma unroll
        for (int n = 0; n < 2; n++) {
          float g = acc[m][n][reg], u = acc[m][n + 2][reg];
          float a = g / (1.f + expf(-g)) * u;
          act[(size_t)(off + rr) * FDIM + c0 + wc * 32 + n * 16 + l15] = f2bf(a);
        }
      }
    }
  }
}

__global__ __launch_bounds__(256) void k_gemm2_fb(
    const float* __restrict__ wdn, const float* __restrict__ sdn,
    const int* __restrict__ wsI, const unsigned short* __restrict__ act,
    float* __restrict__ out)
{
  const int e = blockIdx.y; const int cnt = wsI[e];
  const int r0 = blockIdx.x * 128; if (r0 >= cnt) return;
  const int off = wsI[16 + e]; const int c0 = blockIdx.z * 128;
  const int* etok = wsI + ETOK_OFF;
  const float* ew = (const float*)(wsI + ETOK_OFF + NENT);
  __shared__ unsigned short As[128][40]; __shared__ unsigned short Bs[128][40];
  const int tid = threadIdx.x, lane = tid & 63, wv = tid >> 6;
  const int wr = (wv >> 1) * 64, wc = wv & 1, kg = lane >> 4, l15 = lane & 15;
  floatx4 acc[4][4] = {};
  for (int k0 = 0; k0 < FDIM; k0 += 32) {
#pragma unroll
    for (int c = tid; c < 512; c += 256) {
      int row = c >> 2, k8 = c & 3;
      int rg = r0 + row; if (rg >= cnt) rg = cnt - 1;
      short8v v = *(const short8v*)&act[(size_t)(off + rg) * FDIM + k0 + k8 * 8];
      *(short8v*)&As[row][k8 * 8] = v;
    }
#pragma unroll
    for (int c = tid; c < 1024; c += 256) {
      int row = c >> 3, k4 = c & 7;
      int gr = c0 + row;
      float s = sdn[e * 128 + (gr >> 7) * 8 + (k0 >> 7)];
      const floatx4 v = *(const floatx4*)&wdn[((size_t)e * HDIM + gr) * FDIM + k0 + k4 * 4];
      ushort4v o = { f2bf(v.x * s), f2bf(v.y * s), f2bf(v.z * s), f2bf(v.w * s) };
      *(ushort4v*)&Bs[row][k4 * 4] = o;
    }
    __syncthreads();
    short8v a[4], b[4];
#pragma unroll
    for (int m = 0; m < 4; m++) a[m] = *(const short8v*)&As[wr + m * 16 + l15][kg * 8];
#pragma unroll
    for (int n = 0; n < 4; n++) b[n] = *(const short8v*)&Bs[wc * 64 + n * 16 + l15][kg * 8];
#pragma unroll
    for (int m = 0; m < 4; m++)
#pragma unroll
      for (int n = 0; n < 4; n++)
        acc[m][n] = __builtin_amdgcn_mfma_f32_16x16x32_bf16(a[m], b[n], acc[m][n], 0, 0, 0);
    __syncthreads();
  }
#pragma unroll
  for (int m = 0; m < 4; m++) {
    int rbase = r0 + wr + m * 16 + kg * 4;
#pragma unroll
    for (int reg = 0; reg < 4; reg++) {
      int rr = rbase + reg;
      if (rr < cnt) {
        int tok = etok[off + rr];
        float ww = ew[off + rr];
#pragma unroll
        for (int n = 0; n < 4; n++)
          atomicAdd(&out[(size_t)tok * HDIM + c0 + wc * 64 + n * 16 + l15], ww * acc[m][n][reg]);
      }
    }
  }
}

extern "C" void kernel_launch(void* const* d_in, const int* in_sizes, int n_in,
                              void* d_out, int out_size, void* d_ws, size_t ws_size,
                              hipStream_t stream) {
  const float* hidden = (const float*)d_in[0];
  const float* tw     = (const float*)d_in[1];
  const int*   ids    = (const int*)d_in[2];
  const float* wgu    = (const float*)d_in[3];
  const float* sgu    = (const float*)d_in[4];
  const float* wdn    = (const float*)d_in[5];
  const float* sdn    = (const float*)d_in[6];
  float* out = (float*)d_out;
  int* wsI = (int*)d_ws;

  hipMemsetAsync(d_ws, 0, 512, stream);
  k_count  <<<16, 256, 0, stream>>>(ids, wsI);
  k_scan   <<<1, 1, 0, stream>>>(wsI);
  k_scatter<<<16, 256, 0, stream>>>(ids, tw, wsI);

  const size_t NEED = 65536ull + (52ull << 20);
  if (ws_size >= NEED) {
    unsigned short* hb  = (unsigned short*)((char*)d_ws + 65536);
    unsigned short* act = hb + (size_t)T_TOK * HDIM;
    float*          oe  = (float*)(act + (size_t)NENT * FDIM);

    k_cast_h<<<2048, 256, 0, stream>>>(hidden, hb);

    dim3 g1(WMAX, 32);
    k_gemm1n<<<g1, 256, 0, stream>>>(hb, wgu, sgu, wsI, act);
    dim3 g2(WMAX, 32);
    k_gemm2n<<<g2, 256, 0, stream>>>(wdn, sdn, wsI, act, oe);
    k_reduce<<<T_TOK * HDIM / 4 / 256, 256, 0, stream>>>(wsI, oe, out);
  } else {
    unsigned short* act = (unsigned short*)((char*)d_ws + 65536);
    hipMemsetAsync(d_out, 0, (size_t)T_TOK * HDIM * sizeof(float), stream);
    dim3 g1(NENT / 128, NEXP, FDIM / 64);
    k_gemm1_fb<<<g1, 256, 0, stream>>>(hidden, wgu, sgu, wsI, act);
    dim3 g2(NENT / 128, NEXP, HDIM / 128);
    k_gemm2_fb<<<g2, 256, 0, stream>>>(wdn, sdn, wsI, act, out);
  }
}

// Round 8
// 233.131 us; speedup vs baseline: 1.0735x; 1.0735x over previous
//
#include <hip/hip_runtime.h>
#include <hip/hip_bf16.h>

#define T_TOK 2048
#define HDIM  2048
#define FDIM  1024
#define NEXP  8
#define KSEL  2
#define NENT  (T_TOK*KSEL)   // 4096 routing entries
#define WMAX  24             // max 256-row work items

typedef __attribute__((ext_vector_type(8))) short   short8v;
typedef __attribute__((ext_vector_type(4))) float   floatx4;
typedef __attribute__((ext_vector_type(4))) unsigned short ushort4v;

__device__ __forceinline__ unsigned short f2bf(float f) {
  unsigned int u = __builtin_bit_cast(unsigned int, f);
  u += 0x7FFFu + ((u >> 16) & 1u);
  return (unsigned short)(u >> 16);
}

__device__ __forceinline__ void gll16(const void* g, void* l) {
  __builtin_amdgcn_global_load_lds(
      (const __attribute__((address_space(1))) unsigned int*)g,
      (__attribute__((address_space(3))) unsigned int*)l, 16, 0, 0);
}

// ---- workspace layout ----
// wsI[0:8) cnt | wsI[8:16) cursor | wsI[16:24) offsets | wsI[24] nWork
// wsI[48:72) work list (e<<8 | block256)
// wsI[128:128+4096) entry token | (float*)[4096] entry weight
// byte 65536: hidden_bf (8 MiB) | act (8 MiB)
#define ETOK_OFF 128

__global__ void k_count(const int* __restrict__ ids, int* __restrict__ wsI) {
  int g = blockIdx.x * 256 + threadIdx.x;
  if (g < NENT) atomicAdd(&wsI[ids[g] & 7], 1);
}

__global__ void k_scan(int* __restrict__ wsI) {
  int s = 0, nW = 0;
  int* wl = wsI + 48;
  for (int e = 0; e < NEXP; e++) {
    wsI[16 + e] = s;
    int c = wsI[e];
    s += c;
    int nb = (c + 255) >> 8;
    for (int sb = 0; sb < nb; sb++) wl[nW++] = (e << 8) | sb;
  }
  wsI[24] = nW;
}

__global__ void k_scatter(const int* __restrict__ ids, const float* __restrict__ tw,
                          int* __restrict__ wsI) {
  int g = blockIdx.x * 256 + threadIdx.x;
  if (g >= NENT) return;
  int e = ids[g] & 7;
  int pos = atomicAdd(&wsI[8 + e], 1);
  int idx = wsI[16 + e] + pos;
  int*   etok = wsI + ETOK_OFF;
  float* ew   = (float*)(wsI + ETOK_OFF + NENT);
  etok[idx] = g >> 1;
  ew[idx]   = tw[g];
}

__global__ __launch_bounds__(256) void k_cast_h(const float* __restrict__ h,
                                                unsigned short* __restrict__ o) {
  const int N = T_TOK * HDIM / 8;
  for (int c = blockIdx.x * 256 + threadIdx.x; c < N; c += 2048 * 256) {
    const floatx4 v0 = *(const floatx4*)(h + (size_t)c * 8);
    const floatx4 v1 = *(const floatx4*)(h + (size_t)c * 8 + 4);
    short8v r = { (short)f2bf(v0.x), (short)f2bf(v0.y), (short)f2bf(v0.z), (short)f2bf(v0.w),
                  (short)f2bf(v1.x), (short)f2bf(v1.y), (short)f2bf(v1.z), (short)f2bf(v1.w) };
    *(short8v*)(o + (size_t)c * 8) = r;
  }
}

// pipelined step: issue stage(T+1) (12 vmem ops stay in flight across the
// barrier), cvt+ds_write B(T), lgkmcnt(0)+raw barrier (NO vmcnt drain),
// compute(T), raw barrier.
#define PIPE_STEP(TT, BUF, CUR, NXT, NT, SRC_A)                                 \
  do {                                                                          \
    if ((TT) + 1 < (NT)) {                                                      \
      const int kn = ((TT) + 1) * 64;                                           \
      _Pragma("unroll")                                                         \
      for (int i = 0; i < 8; i++)                                               \
        gll16(SRC_A + aoff[i] + kn, (char*)As[(BUF) ^ 1] + (w * 8 + i) * 1024); \
      __builtin_amdgcn_sched_barrier(0);                                        \
      _Pragma("unroll")                                                         \
      for (int cc = 0; cc < 2; cc++) {                                          \
        NXT[cc * 2]     = *(const floatx4*)(bsrc[cc] + kn);                     \
        NXT[cc * 2 + 1] = *(const floatx4*)(bsrc[cc] + kn + 4);                 \
      }                                                                         \
      __builtin_amdgcn_sched_barrier(0);                                        \
    }                                                                           \
    _Pragma("unroll")                                                           \
    for (int cc = 0; cc < 2; cc++) {                                            \
      float sc = bsrow[cc][(TT) >> 1];                                          \
      floatx4 v0 = CUR[cc * 2], v1 = CUR[cc * 2 + 1];                           \
      short8v r8 = { (short)f2bf(v0.x*sc), (short)f2bf(v0.y*sc),                \
                     (short)f2bf(v0.z*sc), (short)f2bf(v0.w*sc),                \
                     (short)f2bf(v1.x*sc), (short)f2bf(v1.y*sc),                \
                     (short)f2bf(v1.z*sc), (short)f2bf(v1.w*sc) };              \
      *(short8v*)((char*)Bs[BUF] + bdst[cc]) = r8;                              \
    }                                                                           \
    asm volatile("s_waitcnt lgkmcnt(0)" ::: "memory");                          \
    __builtin_amdgcn_s_barrier();                                               \
    __builtin_amdgcn_sched_barrier(0);                                          \
    {                                                                           \
      const char* Ab = (const char*)As[BUF];                                    \
      const char* Bb = (const char*)Bs[BUF];                                    \
      _Pragma("unroll")                                                         \
      for (int ks = 0; ks < 2; ks++) {                                          \
        short8v a[4], b[4];                                                     \
        _Pragma("unroll")                                                       \
        for (int m = 0; m < 4; m++) {                                           \
          int r = w * 64 + m * 16 + l15;                                        \
          a[m] = *(const short8v*)(Ab + r * 128 + (((ks*4+kg) ^ (r & 7)) << 4));\
        }                                                                       \
        _Pragma("unroll")                                                       \
        for (int n = 0; n < 4; n++) {                                           \
          int rb = n * 16 + l15;                                                \
          b[n] = *(const short8v*)(Bb + rb * 128 + (((ks*4+kg) ^ (rb & 7)) << 4)); \
        }                                                                       \
        _Pragma("unroll")                                                       \
        for (int m = 0; m < 4; m++)                                             \
          _Pragma("unroll")                                                     \
          for (int n = 0; n < 4; n++)                                           \
            acc[m][n] = __builtin_amdgcn_mfma_f32_16x16x32_bf16(a[m], b[n], acc[m][n], 0, 0, 0); \
      }                                                                         \
    }                                                                           \
    __builtin_amdgcn_sched_barrier(0);                                          \
    __builtin_amdgcn_s_barrier();                                               \
    __builtin_amdgcn_sched_barrier(0);                                          \
  } while (0)

// ---- GEMM1: act = silu(h@Wg^T)*(h@Wu^T); BM=256, pipelined; fused dequant ----
// grid (WMAX, 32): y = 32 act cols (B = 32 gate + 32 up rows), BK=64, NT=32.
__global__ __launch_bounds__(256, 2) void k_gemm1n(
    const unsigned short* __restrict__ hb,
    const float* __restrict__ wgu,
    const float* __restrict__ sgu,
    const int* __restrict__ wsI,
    unsigned short* __restrict__ act)
{
  if ((int)blockIdx.x >= wsI[24]) return;
  const int item = wsI[48 + blockIdx.x];
  const int e    = item >> 8;
  const int r0   = (item & 255) << 8;
  const int cnt  = wsI[e];
  const int off  = wsI[16 + e];
  const int c0   = blockIdx.y * 32;
  const int* etok = wsI + ETOK_OFF;

  __shared__ unsigned short As[2][256][64];  // 64 KB
  __shared__ unsigned short Bs[2][64][64];   // 16 KB

  const int tid = threadIdx.x, lane = tid & 63, w = tid >> 6;
  const int kg = lane >> 4, l15 = lane & 15, lr = lane >> 3, lc = lane & 7;

  unsigned int aoff[8];
#pragma unroll
  for (int i = 0; i < 8; i++) {
    int ra  = w * 64 + i * 8 + lr;
    int swz = (lc ^ (ra & 7)) * 8;
    int ent = r0 + ra; if (ent >= cnt) ent = cnt - 1;
    aoff[i] = (unsigned)etok[off + ent] * 2048u + (unsigned)swz;
  }

  const float* bsrc[2]; const float* bsrow[2]; int bdst[2];
#pragma unroll
  for (int cc = 0; cc < 2; cc++) {
    int c = tid + cc * 256;
    int row = c >> 3, ch = c & 7;
    int gr = (row < 32) ? (c0 + row) : (1024 + c0 + row - 32);
    bsrc[cc]  = &wgu[((size_t)e * 2048 + gr) * 2048 + ch * 8];
    bsrow[cc] = &sgu[e * 256 + (gr >> 7) * 16];
    bdst[cc]  = row * 128 + ((ch ^ (row & 7)) << 4);
  }

  floatx4 acc[4][4] = {};
  floatx4 rA[4], rB[4];

  // prologue: issue stage(0) into buf0 / rA
#pragma unroll
  for (int i = 0; i < 8; i++)
    gll16(hb + aoff[i], (char*)As[0] + (w * 8 + i) * 1024);
  __builtin_amdgcn_sched_barrier(0);
#pragma unroll
  for (int cc = 0; cc < 2; cc++) {
    rA[cc * 2]     = *(const floatx4*)(bsrc[cc]);
    rA[cc * 2 + 1] = *(const floatx4*)(bsrc[cc] + 4);
  }
  __builtin_amdgcn_sched_barrier(0);

  for (int t = 0; t < 32; t += 2) {
    PIPE_STEP(t,     0, rA, rB, 32, hb);
    PIPE_STEP(t + 1, 1, rB, rA, 32, hb);
  }

#pragma unroll
  for (int m = 0; m < 4; m++) {
    int rbase = r0 + w * 64 + m * 16 + kg * 4;
#pragma unroll
    for (int reg = 0; reg < 4; reg++) {
      int rr = rbase + reg;
      if (rr < cnt) {
#pragma unroll
        for (int n = 0; n < 2; n++) {
          float g = acc[m][n][reg];
          float u = acc[m][n + 2][reg];
          float a = g / (1.f + __expf(-g)) * u;
          act[(size_t)(off + rr) * FDIM + c0 + n * 16 + l15] = f2bf(a);
        }
      }
    }
  }
}

// ---- GEMM2: out[tok] += w_entry * (act @ Wdn^T); BM=256, pipelined ----
// grid (WMAX, 32): y = 64 h cols (B = 64 rows), BK=64, NT=16. Atomic epilogue.
__global__ __launch_bounds__(256, 2) void k_gemm2n(
    const float* __restrict__ wdn,
    const float* __restrict__ sdn,
    const int* __restrict__ wsI,
    const unsigned short* __restrict__ act,
    float* __restrict__ out)
{
  if ((int)blockIdx.x >= wsI[24]) return;
  const int item = wsI[48 + blockIdx.x];
  const int e    = item >> 8;
  const int r0   = (item & 255) << 8;
  const int cnt  = wsI[e];
  const int off  = wsI[16 + e];
  const int c0   = blockIdx.y * 64;
  const int* etok = wsI + ETOK_OFF;
  const float* ew = (const float*)(wsI + ETOK_OFF + NENT);

  __shared__ unsigned short As[2][256][64];  // 64 KB
  __shared__ unsigned short Bs[2][64][64];   // 16 KB

  const int tid = threadIdx.x, lane = tid & 63, w = tid >> 6;
  const int kg = lane >> 4, l15 = lane & 15, lr = lane >> 3, lc = lane & 7;

  unsigned int aoff[8];
#pragma unroll
  for (int i = 0; i < 8; i++) {
    int ra  = w * 64 + i * 8 + lr;
    int swz = (lc ^ (ra & 7)) * 8;
    int ent = r0 + ra; if (ent >= cnt) ent = cnt - 1;
    aoff[i] = (unsigned)(off + ent) * 1024u + (unsigned)swz;
  }

  const float* bsrc[2]; const float* bsrow[2]; int bdst[2];
#pragma unroll
  for (int cc = 0; cc < 2; cc++) {
    int c = tid + cc * 256;
    int row = c >> 3, ch = c & 7;
    int gr = c0 + row;
    bsrc[cc]  = &wdn[((size_t)e * 2048 + gr) * 1024 + ch * 8];
    bsrow[cc] = &sdn[e * 128 + (gr >> 7) * 8];
    bdst[cc]  = row * 128 + ((ch ^ (row & 7)) << 4);
  }

  floatx4 acc[4][4] = {};
  floatx4 rA[4], rB[4];

#pragma unroll
  for (int i = 0; i < 8; i++)
    gll16(act + aoff[i], (char*)As[0] + (w * 8 + i) * 1024);
  __builtin_amdgcn_sched_barrier(0);
#pragma unroll
  for (int cc = 0; cc < 2; cc++) {
    rA[cc * 2]     = *(const floatx4*)(bsrc[cc]);
    rA[cc * 2 + 1] = *(const floatx4*)(bsrc[cc] + 4);
  }
  __builtin_amdgcn_sched_barrier(0);

  for (int t = 0; t < 16; t += 2) {
    PIPE_STEP(t,     0, rA, rB, 16, act);
    PIPE_STEP(t + 1, 1, rB, rA, 16, act);
  }

#pragma unroll
  for (int m = 0; m < 4; m++) {
    int rbase = r0 + w * 64 + m * 16 + kg * 4;
#pragma unroll
    for (int reg = 0; reg < 4; reg++) {
      int rr = rbase + reg;
      if (rr < cnt) {
        int tok   = etok[off + rr];
        float wgt = ew[off + rr];
#pragma unroll
        for (int n = 0; n < 4; n++)
          atomicAdd(&out[(size_t)tok * HDIM + c0 + n * 16 + l15], wgt * acc[m][n][reg]);
      }
    }
  }
}

// ================= fallback (round-1 passing kernels) =================
__global__ __launch_bounds__(256) void k_gemm1_fb(
    const float* __restrict__ hidden, const float* __restrict__ wgu,
    const float* __restrict__ sgu, const int* __restrict__ wsI,
    unsigned short* __restrict__ act)
{
  const int e = blockIdx.y; const int cnt = wsI[e];
  const int r0 = blockIdx.x * 128; if (r0 >= cnt) return;
  const int off = wsI[16 + e]; const int c0 = blockIdx.z * 64;
  const int* etok = wsI + ETOK_OFF;
  __shared__ unsigned short As[128][40]; __shared__ unsigned short Bs[128][40];
  const int tid = threadIdx.x, lane = tid & 63, wv = tid >> 6;
  const int wr = (wv >> 1) * 64, wc = wv & 1, kg = lane >> 4, l15 = lane & 15;
  floatx4 acc[4][4] = {};
  for (int k0 = 0; k0 < HDIM; k0 += 32) {
#pragma unroll
    for (int c = tid; c < 1024; c += 256) {
      int row = c >> 3, k4 = c & 7;
      int rg = r0 + row; if (rg >= cnt) rg = cnt - 1;
      int tok = etok[off + rg];
      const floatx4 v = *(const floatx4*)&hidden[(size_t)tok * HDIM + k0 + k4 * 4];
      ushort4v o = { f2bf(v.x), f2bf(v.y), f2bf(v.z), f2bf(v.w) };
      *(ushort4v*)&As[row][k4 * 4] = o;
    }
#pragma unroll
    for (int c = tid; c < 1024; c += 256) {
      int row = c >> 3, k4 = c & 7;
      int gr = (row < 64) ? (c0 + row) : (FDIM + c0 + row - 64);
      float s = sgu[e * 256 + (gr >> 7) * 16 + (k0 >> 7)];
      const floatx4 v = *(const floatx4*)&wgu[((size_t)e * 2048 + gr) * HDIM + k0 + k4 * 4];
      ushort4v o = { f2bf(v.x * s), f2bf(v.y * s), f2bf(v.z * s), f2bf(v.w * s) };
      *(ushort4v*)&Bs[row][k4 * 4] = o;
    }
    __syncthreads();
    short8v a[4], b[4];
#pragma unroll
    for (int m = 0; m < 4; m++) a[m] = *(const short8v*)&As[wr + m * 16 + l15][kg * 8];
#pragma unroll
    for (int n = 0; n < 4; n++) {
      int br = (n < 2) ? (wc * 32 + n * 16) : (64 + wc * 32 + (n - 2) * 16);
      b[n] = *(const short8v*)&Bs[br + l15][kg * 8];
    }
#pragma unroll
    for (int m = 0; m < 4; m++)
#pragma unroll
      for (int n = 0; n < 4; n++)
        acc[m][n] = __builtin_amdgcn_mfma_f32_16x16x32_bf16(a[m], b[n], acc[m][n], 0, 0, 0);
    __syncthreads();
  }
#pragma unroll
  for (int m = 0; m < 4; m++) {
    int rbase = r0 + wr + m * 16 + kg * 4;
#pragma unroll
    for (int reg = 0; reg < 4; reg++) {
      int rr = rbase + reg;
      if (rr < cnt) {
#pragma unroll
        for (int n = 0; n < 2; n++) {
          float g = acc[m][n][reg], u = acc[m][n + 2][reg];
          float a = g / (1.f + expf(-g)) * u;
          act[(size_t)(off + rr) * FDIM + c0 + wc * 32 + n * 16 + l15] = f2bf(a);
        }
      }
    }
  }
}

__global__ __launch_bounds__(256) void k_gemm2_fb(
    const float* __restrict__ wdn, const float* __restrict__ sdn,
    const int* __restrict__ wsI, const unsigned short* __restrict__ act,
    float* __restrict__ out)
{
  const int e = blockIdx.y; const int cnt = wsI[e];
  const int r0 = blockIdx.x * 128; if (r0 >= cnt) return;
  const int off = wsI[16 + e]; const int c0 = blockIdx.z * 128;
  const int* etok = wsI + ETOK_OFF;
  const float* ew = (const float*)(wsI + ETOK_OFF + NENT);
  __shared__ unsigned short As[128][40]; __shared__ unsigned short Bs[128][40];
  const int tid = threadIdx.x, lane = tid & 63, wv = tid >> 6;
  const int wr = (wv >> 1) * 64, wc = wv & 1, kg = lane >> 4, l15 = lane & 15;
  floatx4 acc[4][4] = {};
  for (int k0 = 0; k0 < FDIM; k0 += 32) {
#pragma unroll
    for (int c = tid; c < 512; c += 256) {
      int row = c >> 2, k8 = c & 3;
      int rg = r0 + row; if (rg >= cnt) rg = cnt - 1;
      short8v v = *(const short8v*)&act[(size_t)(off + rg) * FDIM + k0 + k8 * 8];
      *(short8v*)&As[row][k8 * 8] = v;
    }
#pragma unroll
    for (int c = tid; c < 1024; c += 256) {
      int row = c >> 3, k4 = c & 7;
      int gr = c0 + row;
      float s = sdn[e * 128 + (gr >> 7) * 8 + (k0 >> 7)];
      const floatx4 v = *(const floatx4*)&wdn[((size_t)e * HDIM + gr) * FDIM + k0 + k4 * 4];
      ushort4v o = { f2bf(v.x * s), f2bf(v.y * s), f2bf(v.z * s), f2bf(v.w * s) };
      *(ushort4v*)&Bs[row][k4 * 4] = o;
    }
    __syncthreads();
    short8v a[4], b[4];
#pragma unroll
    for (int m = 0; m < 4; m++) a[m] = *(const short8v*)&As[wr + m * 16 + l15][kg * 8];
#pragma unroll
    for (int n = 0; n < 4; n++) b[n] = *(const short8v*)&Bs[wc * 64 + n * 16 + l15][kg * 8];
#pragma unroll
    for (int m = 0; m < 4; m++)
#pragma unroll
      for (int n = 0; n < 4; n++)
        acc[m][n] = __builtin_amdgcn_mfma_f32_16x16x32_bf16(a[m], b[n], acc[m][n], 0, 0, 0);
    __syncthreads();
  }
#pragma unroll
  for (int m = 0; m < 4; m++) {
    int rbase = r0 + wr + m * 16 + kg * 4;
#pragma unroll
    for (int reg = 0; reg < 4; reg++) {
      int rr = rbase + reg;
      if (rr < cnt) {
        int tok = etok[off + rr];
        float ww = ew[off + rr];
#pragma unroll
        for (int n = 0; n < 4; n++)
          atomicAdd(&out[(size_t)tok * HDIM + c0 + wc * 64 + n * 16 + l15], ww * acc[m][n][reg]);
      }
    }
  }
}

extern "C" void kernel_launch(void* const* d_in, const int* in_sizes, int n_in,
                              void* d_out, int out_size, void* d_ws, size_t ws_size,
                              hipStream_t stream) {
  const float* hidden = (const float*)d_in[0];
  const float* tw     = (const float*)d_in[1];
  const int*   ids    = (const int*)d_in[2];
  const float* wgu    = (const float*)d_in[3];
  const float* sgu    = (const float*)d_in[4];
  const float* wdn    = (const float*)d_in[5];
  const float* sdn    = (const float*)d_in[6];
  float* out = (float*)d_out;
  int* wsI = (int*)d_ws;

  hipMemsetAsync(d_ws, 0, 512, stream);
  hipMemsetAsync(d_out, 0, (size_t)T_TOK * HDIM * sizeof(float), stream);
  k_count  <<<16, 256, 0, stream>>>(ids, wsI);
  k_scan   <<<1, 1, 0, stream>>>(wsI);
  k_scatter<<<16, 256, 0, stream>>>(ids, tw, wsI);

  const size_t NEED = 65536ull + (16ull << 20);
  if (ws_size >= NEED) {
    unsigned short* hb  = (unsigned short*)((char*)d_ws + 65536);
    unsigned short* act = hb + (size_t)T_TOK * HDIM;

    k_cast_h<<<2048, 256, 0, stream>>>(hidden, hb);

    dim3 g1(WMAX, 32);
    k_gemm1n<<<g1, 256, 0, stream>>>(hb, wgu, sgu, wsI, act);
    dim3 g2(WMAX, 32);
    k_gemm2n<<<g2, 256, 0, stream>>>(wdn, sdn, wsI, act, out);
  } else {
    unsigned short* act = (unsigned short*)((char*)d_ws + 65536);
    dim3 g1(NENT / 128, NEXP, FDIM / 64);
    k_gemm1_fb<<<g1, 256, 0, stream>>>(hidden, wgu, sgu, wsI, act);
    dim3 g2(NENT / 128, NEXP, HDIM / 128);
    k_gemm2_fb<<<g2, 256, 0, stream>>>(wdn, sdn, wsI, act, out);
  }
}

// Round 9
// 227.588 us; speedup vs baseline: 1.0997x; 1.0244x over previous
//
#include <hip/hip_runtime.h>
#include <hip/hip_bf16.h>

#define T_TOK 2048
#define HDIM  2048
#define FDIM  1024
#define NEXP  8
#define KSEL  2
#define NENT  (T_TOK*KSEL)   // 4096 routing entries
#define WMAX  24             // max 256-row work items

typedef __attribute__((ext_vector_type(8))) short   short8v;
typedef __attribute__((ext_vector_type(4))) float   floatx4;
typedef __attribute__((ext_vector_type(4))) unsigned short ushort4v;

__device__ __forceinline__ unsigned short f2bf(float f) {
  unsigned int u = __builtin_bit_cast(unsigned int, f);
  u += 0x7FFFu + ((u >> 16) & 1u);
  return (unsigned short)(u >> 16);
}

__device__ __forceinline__ void gll16(const void* g, void* l) {
  __builtin_amdgcn_global_load_lds(
      (const __attribute__((address_space(1))) unsigned int*)g,
      (__attribute__((address_space(3))) unsigned int*)l, 16, 0, 0);
}

// ---- workspace layout ----
// wsI[0:8) cnt | wsI[8:16) cursor | wsI[16:24) offsets | wsI[24] nWork
// wsI[48:72) work list (e<<8 | block256)
// wsI[128:128+4096) entry token | (float*)[4096] entry weight
// byte 65536: hidden_bf (8 MiB) | act (8 MiB)
#define ETOK_OFF 128

__global__ void k_count(const int* __restrict__ ids, int* __restrict__ wsI) {
  int g = blockIdx.x * 256 + threadIdx.x;
  if (g < NENT) atomicAdd(&wsI[ids[g] & 7], 1);
}

__global__ void k_scan(int* __restrict__ wsI) {
  int s = 0, nW = 0;
  int* wl = wsI + 48;
  for (int e = 0; e < NEXP; e++) {
    wsI[16 + e] = s;
    int c = wsI[e];
    s += c;
    int nb = (c + 255) >> 8;
    for (int sb = 0; sb < nb; sb++) wl[nW++] = (e << 8) | sb;
  }
  wsI[24] = nW;
}

__global__ void k_scatter(const int* __restrict__ ids, const float* __restrict__ tw,
                          int* __restrict__ wsI) {
  int g = blockIdx.x * 256 + threadIdx.x;
  if (g >= NENT) return;
  int e = ids[g] & 7;
  int pos = atomicAdd(&wsI[8 + e], 1);
  int idx = wsI[16 + e] + pos;
  int*   etok = wsI + ETOK_OFF;
  float* ew   = (float*)(wsI + ETOK_OFF + NENT);
  etok[idx] = g >> 1;
  ew[idx]   = tw[g];
}

__global__ __launch_bounds__(256) void k_cast_h(const float* __restrict__ h,
                                                unsigned short* __restrict__ o) {
  const int N = T_TOK * HDIM / 8;
  for (int c = blockIdx.x * 256 + threadIdx.x; c < N; c += 2048 * 256) {
    const floatx4 v0 = *(const floatx4*)(h + (size_t)c * 8);
    const floatx4 v1 = *(const floatx4*)(h + (size_t)c * 8 + 4);
    short8v r = { (short)f2bf(v0.x), (short)f2bf(v0.y), (short)f2bf(v0.z), (short)f2bf(v0.w),
                  (short)f2bf(v1.x), (short)f2bf(v1.y), (short)f2bf(v1.z), (short)f2bf(v1.w) };
    *(short8v*)(o + (size_t)c * 8) = r;
  }
}

// One K-iteration of the depth-2 pipeline.
//   A(t):   gll16 into single-buffer As (wave-private rows), drained by vmcnt(4)
//   B(t+2): global->reg loads (stay in flight across barriers; clamped at tail)
//   B(t+1): cvt regs -> ds_write Bs[(t+1)&1]   (just-in-time)
//   compute(t): As + Bs[t&1]
#define PIPE_ITER(TT, CUR, NXT, NT, NTS, SRC_A)                                 \
  do {                                                                          \
    /* A(t) */                                                                  \
    _Pragma("unroll")                                                           \
    for (int i = 0; i < 8; i++)                                                 \
      gll16(SRC_A + aoff[i] + (TT) * 64, (char*)As + (w * 8 + i) * 1024);       \
    __builtin_amdgcn_sched_barrier(0);                                          \
    /* B(t+2) -> NXT (clamped source at tail; regs unused there) */             \
    {                                                                           \
      int kq = (TT) + 2; if (kq > (NT) - 1) kq = (NT) - 1;                      \
      const int kn = kq * 64;                                                   \
      _Pragma("unroll")                                                         \
      for (int cc = 0; cc < 2; cc++) {                                          \
        NXT[cc * 2]     = *(const floatx4*)(bsrc[cc] + kn);                     \
        NXT[cc * 2 + 1] = *(const floatx4*)(bsrc[cc] + kn + 4);                 \
      }                                                                         \
    }                                                                           \
    __builtin_amdgcn_sched_barrier(0);                                          \
    /* cvt B(t+1) -> Bs[(t+1)&1] (clamped scale idx at tail) */                 \
    {                                                                           \
      int si = ((TT) + 1) >> 1; if (si > (NTS) - 1) si = (NTS) - 1;             \
      _Pragma("unroll")                                                         \
      for (int cc = 0; cc < 2; cc++) {                                          \
        float sc = bsrow[cc][si];                                               \
        floatx4 v0 = CUR[cc * 2], v1 = CUR[cc * 2 + 1];                         \
        short8v r8 = { (short)f2bf(v0.x*sc), (short)f2bf(v0.y*sc),              \
                       (short)f2bf(v0.z*sc), (short)f2bf(v0.w*sc),              \
                       (short)f2bf(v1.x*sc), (short)f2bf(v1.y*sc),              \
                       (short)f2bf(v1.z*sc), (short)f2bf(v1.w*sc) };            \
        *(short8v*)((char*)Bs[((TT) + 1) & 1] + bdst[cc]) = r8;                 \
      }                                                                         \
    }                                                                           \
    asm volatile("s_waitcnt lgkmcnt(0)" ::: "memory");                          \
    asm volatile("s_waitcnt vmcnt(4)" ::: "memory");                            \
    __builtin_amdgcn_s_barrier();                                               \
    __builtin_amdgcn_sched_barrier(0);                                          \
    /* compute(t) */                                                            \
    {                                                                           \
      const char* Ab = (const char*)As;                                         \
      const char* Bb = (const char*)Bs[(TT) & 1];                               \
      _Pragma("unroll")                                                         \
      for (int ks = 0; ks < 2; ks++) {                                          \
        short8v a[4], b[4];                                                     \
        _Pragma("unroll")                                                       \
        for (int m = 0; m < 4; m++) {                                           \
          int r = w * 64 + m * 16 + l15;                                        \
          a[m] = *(const short8v*)(Ab + r * 128 + (((ks*4+kg) ^ (r & 7)) << 4));\
        }                                                                       \
        _Pragma("unroll")                                                       \
        for (int n = 0; n < 4; n++) {                                           \
          int rb = n * 16 + l15;                                                \
          b[n] = *(const short8v*)(Bb + rb * 128 + (((ks*4+kg) ^ (rb & 7)) << 4)); \
        }                                                                       \
        _Pragma("unroll")                                                       \
        for (int m = 0; m < 4; m++)                                             \
          _Pragma("unroll")                                                     \
          for (int n = 0; n < 4; n++)                                           \
            acc[m][n] = __builtin_amdgcn_mfma_f32_16x16x32_bf16(a[m], b[n], acc[m][n], 0, 0, 0); \
      }                                                                         \
    }                                                                           \
    __builtin_amdgcn_sched_barrier(0);                                          \
    __builtin_amdgcn_s_barrier();                                               \
    __builtin_amdgcn_sched_barrier(0);                                          \
  } while (0)

// ---- GEMM1: act = silu(h@Wg^T)*(h@Wu^T); BM=256, depth-2 pipeline ----
// grid (WMAX, 32): y = 32 act cols (B = 32 gate + 32 up rows), BK=64, NT=32.
__global__ __launch_bounds__(256, 3) void k_gemm1n(
    const unsigned short* __restrict__ hb,
    const float* __restrict__ wgu,
    const float* __restrict__ sgu,
    const int* __restrict__ wsI,
    unsigned short* __restrict__ act)
{
  if ((int)blockIdx.x >= wsI[24]) return;
  const int item = wsI[48 + blockIdx.x];
  const int e    = item >> 8;
  const int r0   = (item & 255) << 8;
  const int cnt  = wsI[e];
  const int off  = wsI[16 + e];
  const int c0   = blockIdx.y * 32;
  const int* etok = wsI + ETOK_OFF;

  __shared__ unsigned short As[256][64];     // 32 KB (single buffer, wave-private rows)
  __shared__ unsigned short Bs[2][64][64];   // 16 KB

  const int tid = threadIdx.x, lane = tid & 63, w = tid >> 6;
  const int kg = lane >> 4, l15 = lane & 15, lr = lane >> 3, lc = lane & 7;

  unsigned int aoff[8];
#pragma unroll
  for (int i = 0; i < 8; i++) {
    int ra  = w * 64 + i * 8 + lr;
    int swz = (lc ^ (ra & 7)) * 8;
    int ent = r0 + ra; if (ent >= cnt) ent = cnt - 1;
    aoff[i] = (unsigned)etok[off + ent] * 2048u + (unsigned)swz;
  }

  const float* bsrc[2]; const float* bsrow[2]; int bdst[2];
#pragma unroll
  for (int cc = 0; cc < 2; cc++) {
    int c = tid + cc * 256;
    int row = c >> 3, ch = c & 7;
    int gr = (row < 32) ? (c0 + row) : (1024 + c0 + row - 32);
    bsrc[cc]  = &wgu[((size_t)e * 2048 + gr) * 2048 + ch * 8];
    bsrow[cc] = &sgu[e * 256 + (gr >> 7) * 16];
    bdst[cc]  = row * 128 + ((ch ^ (row & 7)) << 4);
  }

  floatx4 acc[4][4] = {};
  floatx4 rX[4], rY[4];

  // prologue: B(0) -> Bs[0]; B(1) -> rX
#pragma unroll
  for (int cc = 0; cc < 2; cc++) {
    floatx4 v0 = *(const floatx4*)(bsrc[cc]);
    floatx4 v1 = *(const floatx4*)(bsrc[cc] + 4);
    float sc = bsrow[cc][0];
    short8v r8 = { (short)f2bf(v0.x*sc), (short)f2bf(v0.y*sc), (short)f2bf(v0.z*sc), (short)f2bf(v0.w*sc),
                   (short)f2bf(v1.x*sc), (short)f2bf(v1.y*sc), (short)f2bf(v1.z*sc), (short)f2bf(v1.w*sc) };
    *(short8v*)((char*)Bs[0] + bdst[cc]) = r8;
  }
#pragma unroll
  for (int cc = 0; cc < 2; cc++) {
    rX[cc * 2]     = *(const floatx4*)(bsrc[cc] + 64);
    rX[cc * 2 + 1] = *(const floatx4*)(bsrc[cc] + 64 + 4);
  }
  __builtin_amdgcn_sched_barrier(0);

  for (int t = 0; t < 32; t += 2) {
    PIPE_ITER(t,     rX, rY, 32, 16, hb);
    PIPE_ITER(t + 1, rY, rX, 32, 16, hb);
  }

#pragma unroll
  for (int m = 0; m < 4; m++) {
    int rbase = r0 + w * 64 + m * 16 + kg * 4;
#pragma unroll
    for (int reg = 0; reg < 4; reg++) {
      int rr = rbase + reg;
      if (rr < cnt) {
#pragma unroll
        for (int n = 0; n < 2; n++) {
          float g = acc[m][n][reg];
          float u = acc[m][n + 2][reg];
          float a = g / (1.f + __expf(-g)) * u;
          act[(size_t)(off + rr) * FDIM + c0 + n * 16 + l15] = f2bf(a);
        }
      }
    }
  }
}

// ---- GEMM2: out[tok] += w_entry * (act @ Wdn^T); BM=256, depth-2 pipeline ----
// grid (WMAX, 32): y = 64 h cols (B = 64 rows), BK=64, NT=16. Atomic epilogue.
__global__ __launch_bounds__(256, 3) void k_gemm2n(
    const float* __restrict__ wdn,
    const float* __restrict__ sdn,
    const int* __restrict__ wsI,
    const unsigned short* __restrict__ act,
    float* __restrict__ out)
{
  if ((int)blockIdx.x >= wsI[24]) return;
  const int item = wsI[48 + blockIdx.x];
  const int e    = item >> 8;
  const int r0   = (item & 255) << 8;
  const int cnt  = wsI[e];
  const int off  = wsI[16 + e];
  const int c0   = blockIdx.y * 64;
  const int* etok = wsI + ETOK_OFF;
  const float* ew = (const float*)(wsI + ETOK_OFF + NENT);

  __shared__ unsigned short As[256][64];     // 32 KB
  __shared__ unsigned short Bs[2][64][64];   // 16 KB

  const int tid = threadIdx.x, lane = tid & 63, w = tid >> 6;
  const int kg = lane >> 4, l15 = lane & 15, lr = lane >> 3, lc = lane & 7;

  unsigned int aoff[8];
#pragma unroll
  for (int i = 0; i < 8; i++) {
    int ra  = w * 64 + i * 8 + lr;
    int swz = (lc ^ (ra & 7)) * 8;
    int ent = r0 + ra; if (ent >= cnt) ent = cnt - 1;
    aoff[i] = (unsigned)(off + ent) * 1024u + (unsigned)swz;
  }

  const float* bsrc[2]; const float* bsrow[2]; int bdst[2];
#pragma unroll
  for (int cc = 0; cc < 2; cc++) {
    int c = tid + cc * 256;
    int row = c >> 3, ch = c & 7;
    int gr = c0 + row;
    bsrc[cc]  = &wdn[((size_t)e * 2048 + gr) * 1024 + ch * 8];
    bsrow[cc] = &sdn[e * 128 + (gr >> 7) * 8];
    bdst[cc]  = row * 128 + ((ch ^ (row & 7)) << 4);
  }

  floatx4 acc[4][4] = {};
  floatx4 rX[4], rY[4];

#pragma unroll
  for (int cc = 0; cc < 2; cc++) {
    floatx4 v0 = *(const floatx4*)(bsrc[cc]);
    floatx4 v1 = *(const floatx4*)(bsrc[cc] + 4);
    float sc = bsrow[cc][0];
    short8v r8 = { (short)f2bf(v0.x*sc), (short)f2bf(v0.y*sc), (short)f2bf(v0.z*sc), (short)f2bf(v0.w*sc),
                   (short)f2bf(v1.x*sc), (short)f2bf(v1.y*sc), (short)f2bf(v1.z*sc), (short)f2bf(v1.w*sc) };
    *(short8v*)((char*)Bs[0] + bdst[cc]) = r8;
  }
#pragma unroll
  for (int cc = 0; cc < 2; cc++) {
    rX[cc * 2]     = *(const floatx4*)(bsrc[cc] + 64);
    rX[cc * 2 + 1] = *(const floatx4*)(bsrc[cc] + 64 + 4);
  }
  __builtin_amdgcn_sched_barrier(0);

  for (int t = 0; t < 16; t += 2) {
    PIPE_ITER(t,     rX, rY, 16, 8, act);
    PIPE_ITER(t + 1, rY, rX, 16, 8, act);
  }

#pragma unroll
  for (int m = 0; m < 4; m++) {
    int rbase = r0 + w * 64 + m * 16 + kg * 4;
#pragma unroll
    for (int reg = 0; reg < 4; reg++) {
      int rr = rbase + reg;
      if (rr < cnt) {
        int tok   = etok[off + rr];
        float wgt = ew[off + rr];
#pragma unroll
        for (int n = 0; n < 4; n++)
          atomicAdd(&out[(size_t)tok * HDIM + c0 + n * 16 + l15], wgt * acc[m][n][reg]);
      }
    }
  }
}

// ================= fallback (round-1 passing kernels) =================
__global__ __launch_bounds__(256) void k_gemm1_fb(
    const float* __restrict__ hidden, const float* __restrict__ wgu,
    const float* __restrict__ sgu, const int* __restrict__ wsI,
    unsigned short* __restrict__ act)
{
  const int e = blockIdx.y; const int cnt = wsI[e];
  const int r0 = blockIdx.x * 128; if (r0 >= cnt) return;
  const int off = wsI[16 + e]; const int c0 = blockIdx.z * 64;
  const int* etok = wsI + ETOK_OFF;
  __shared__ unsigned short As[128][40]; __shared__ unsigned short Bs[128][40];
  const int tid = threadIdx.x, lane = tid & 63, wv = tid >> 6;
  const int wr = (wv >> 1) * 64, wc = wv & 1, kg = lane >> 4, l15 = lane & 15;
  floatx4 acc[4][4] = {};
  for (int k0 = 0; k0 < HDIM; k0 += 32) {
#pragma unroll
    for (int c = tid; c < 1024; c += 256) {
      int row = c >> 3, k4 = c & 7;
      int rg = r0 + row; if (rg >= cnt) rg = cnt - 1;
      int tok = etok[off + rg];
      const floatx4 v = *(const floatx4*)&hidden[(size_t)tok * HDIM + k0 + k4 * 4];
      ushort4v o = { f2bf(v.x), f2bf(v.y), f2bf(v.z), f2bf(v.w) };
      *(ushort4v*)&As[row][k4 * 4] = o;
    }
#pragma unroll
    for (int c = tid; c < 1024; c += 256) {
      int row = c >> 3, k4 = c & 7;
      int gr = (row < 64) ? (c0 + row) : (FDIM + c0 + row - 64);
      float s = sgu[e * 256 + (gr >> 7) * 16 + (k0 >> 7)];
      const floatx4 v = *(const floatx4*)&wgu[((size_t)e * 2048 + gr) * HDIM + k0 + k4 * 4];
      ushort4v o = { f2bf(v.x * s), f2bf(v.y * s), f2bf(v.z * s), f2bf(v.w * s) };
      *(ushort4v*)&Bs[row][k4 * 4] = o;
    }
    __syncthreads();
    short8v a[4], b[4];
#pragma unroll
    for (int m = 0; m < 4; m++) a[m] = *(const short8v*)&As[wr + m * 16 + l15][kg * 8];
#pragma unroll
    for (int n = 0; n < 4; n++) {
      int br = (n < 2) ? (wc * 32 + n * 16) : (64 + wc * 32 + (n - 2) * 16);
      b[n] = *(const short8v*)&Bs[br + l15][kg * 8];
    }
#pragma unroll
    for (int m = 0; m < 4; m++)
#pragma unroll
      for (int n = 0; n < 4; n++)
        acc[m][n] = __builtin_amdgcn_mfma_f32_16x16x32_bf16(a[m], b[n], acc[m][n], 0, 0, 0);
    __syncthreads();
  }
#pragma unroll
  for (int m = 0; m < 4; m++) {
    int rbase = r0 + wr + m * 16 + kg * 4;
#pragma unroll
    for (int reg = 0; reg < 4; reg++) {
      int rr = rbase + reg;
      if (rr < cnt) {
#pragma unroll
        for (int n = 0; n < 2; n++) {
          float g = acc[m][n][reg], u = acc[m][n + 2][reg];
          float a = g / (1.f + expf(-g)) * u;
          act[(size_t)(off + rr) * FDIM + c0 + wc * 32 + n * 16 + l15] = f2bf(a);
        }
      }
    }
  }
}

__global__ __launch_bounds__(256) void k_gemm2_fb(
    const float* __restrict__ wdn, const float* __restrict__ sdn,
    const int* __restrict__ wsI, const unsigned short* __restrict__ act,
    float* __restrict__ out)
{
  const int e = blockIdx.y; const int cnt = wsI[e];
  const int r0 = blockIdx.x * 128; if (r0 >= cnt) return;
  const int off = wsI[16 + e]; const int c0 = blockIdx.z * 128;
  const int* etok = wsI + ETOK_OFF;
  const float* ew = (const float*)(wsI + ETOK_OFF + NENT);
  __shared__ unsigned short As[128][40]; __shared__ unsigned short Bs[128][40];
  const int tid = threadIdx.x, lane = tid & 63, wv = tid >> 6;
  const int wr = (wv >> 1) * 64, wc = wv & 1, kg = lane >> 4, l15 = lane & 15;
  floatx4 acc[4][4] = {};
  for (int k0 = 0; k0 < FDIM; k0 += 32) {
#pragma unroll
    for (int c = tid; c < 512; c += 256) {
      int row = c >> 2, k8 = c & 3;
      int rg = r0 + row; if (rg >= cnt) rg = cnt - 1;
      short8v v = *(const short8v*)&act[(size_t)(off + rg) * FDIM + k0 + k8 * 8];
      *(short8v*)&As[row][k8 * 8] = v;
    }
#pragma unroll
    for (int c = tid; c < 1024; c += 256) {
      int row = c >> 3, k4 = c & 7;
      int gr = c0 + row;
      float s = sdn[e * 128 + (gr >> 7) * 8 + (k0 >> 7)];
      const floatx4 v = *(const floatx4*)&wdn[((size_t)e * HDIM + gr) * FDIM + k0 + k4 * 4];
      ushort4v o = { f2bf(v.x * s), f2bf(v.y * s), f2bf(v.z * s), f2bf(v.w * s) };
      *(ushort4v*)&Bs[row][k4 * 4] = o;
    }
    __syncthreads();
    short8v a[4], b[4];
#pragma unroll
    for (int m = 0; m < 4; m++) a[m] = *(const short8v*)&As[wr + m * 16 + l15][kg * 8];
#pragma unroll
    for (int n = 0; n < 4; n++) b[n] = *(const short8v*)&Bs[wc * 64 + n * 16 + l15][kg * 8];
#pragma unroll
    for (int m = 0; m < 4; m++)
#pragma unroll
      for (int n = 0; n < 4; n++)
        acc[m][n] = __builtin_amdgcn_mfma_f32_16x16x32_bf16(a[m], b[n], acc[m][n], 0, 0, 0);
    __syncthreads();
  }
#pragma unroll
  for (int m = 0; m < 4; m++) {
    int rbase = r0 + wr + m * 16 + kg * 4;
#pragma unroll
    for (int reg = 0; reg < 4; reg++) {
      int rr = rbase + reg;
      if (rr < cnt) {
        int tok = etok[off + rr];
        float ww = ew[off + rr];
#pragma unroll
        for (int n = 0; n < 4; n++)
          atomicAdd(&out[(size_t)tok * HDIM + c0 + wc * 64 + n * 16 + l15], ww * acc[m][n][reg]);
      }
    }
  }
}

extern "C" void kernel_launch(void* const* d_in, const int* in_sizes, int n_in,
                              void* d_out, int out_size, void* d_ws, size_t ws_size,
                              hipStream_t stream) {
  const float* hidden = (const float*)d_in[0];
  const float* tw     = (const float*)d_in[1];
  const int*   ids    = (const int*)d_in[2];
  const float* wgu    = (const float*)d_in[3];
  const float* sgu    = (const float*)d_in[4];
  const float* wdn    = (const float*)d_in[5];
  const float* sdn    = (const float*)d_in[6];
  float* out = (float*)d_out;
  int* wsI = (int*)d_ws;

  hipMemsetAsync(d_ws, 0, 512, stream);
  hipMemsetAsync(d_out, 0, (size_t)T_TOK * HDIM * sizeof(float), stream);
  k_count  <<<16, 256, 0, stream>>>(ids, wsI);
  k_scan   <<<1, 1, 0, stream>>>(wsI);
  k_scatter<<<16, 256, 0, stream>>>(ids, tw, wsI);

  const size_t NEED = 65536ull + (16ull << 20);
  if (ws_size >= NEED) {
    unsigned short* hb  = (unsigned short*)((char*)d_ws + 65536);
    unsigned short* act = hb + (size_t)T_TOK * HDIM;

    k_cast_h<<<2048, 256, 0, stream>>>(hidden, hb);

    dim3 g1(WMAX, 32);
    k_gemm1n<<<g1, 256, 0, stream>>>(hb, wgu, sgu, wsI, act);
    dim3 g2(WMAX, 32);
    k_gemm2n<<<g2, 256, 0, stream>>>(wdn, sdn, wsI, act, out);
  } else {
    unsigned short* act = (unsigned short*)((char*)d_ws + 65536);
    dim3 g1(NENT / 128, NEXP, FDIM / 64);
    k_gemm1_fb<<<g1, 256, 0, stream>>>(hidden, wgu, sgu, wsI, act);
    dim3 g2(NENT / 128, NEXP, HDIM / 128);
    k_gemm2_fb<<<g2, 256, 0, stream>>>(wdn, sdn, wsI, act, out);
  }
}